// Round 1
// baseline (633.230 us; speedup 1.0000x reference)
//
#include <hip/hip_runtime.h>

typedef unsigned short u16;
typedef unsigned int u32;
typedef __attribute__((ext_vector_type(4))) float f32x4;
typedef __attribute__((ext_vector_type(8))) short bf16x8;   // 8 bf16 (4 VGPRs) MFMA frag
typedef __attribute__((ext_vector_type(4))) u16 u16x4;
typedef __attribute__((ext_vector_type(8))) u16 u16x8;

// B=8, S=2048, D=1024
#define NB 8
#define NS 2048
#define ND 1024

__device__ __forceinline__ u16 f2bf(float x) {  // f32 -> bf16 round-nearest-even
  u32 u = __builtin_bit_cast(u32, x);
  u32 r = 0x7fffu + ((u >> 16) & 1u);
  return (u16)((u + r) >> 16);
}
__device__ __forceinline__ float bf2f(u16 h) {
  return __builtin_bit_cast(float, (u32)h << 16);
}

// ---------------- elementwise split: x -> (hi, lo) bf16 ----------------
__global__ __launch_bounds__(256) void split_bf16_kernel(
    const float* __restrict__ x, u16* __restrict__ hi, u16* __restrict__ lo, int n4) {
  int i = blockIdx.x * 256 + threadIdx.x;
  const int stride = gridDim.x * 256;
  for (; i < n4; i += stride) {
    f32x4 v = ((const f32x4*)x)[i];
    u16x4 h, l;
#pragma unroll
    for (int j = 0; j < 4; ++j) {
      float f = v[j];
      u16 hh = f2bf(f);
      h[j] = hh;
      l[j] = f2bf(f - bf2f(hh));
    }
    ((u16x4*)hi)[i] = h;
    ((u16x4*)lo)[i] = l;
  }
}

// ---------------- text1 [b][t][d] f32 -> text1T [b][d][t] bf16 ----------------
__global__ __launch_bounds__(256) void transpose_bf16_kernel(
    const float* __restrict__ t1, u16* __restrict__ t1T) {
  __shared__ float tile[32][33];
  const int b = blockIdx.z;
  const float* src = t1 + (size_t)b * (NS * ND);
  u16* dst = t1T + (size_t)b * (ND * NS);
  const int t0 = blockIdx.x * 32, d0 = blockIdx.y * 32;
  const int tx = threadIdx.x, ty = threadIdx.y;  // (32,8)
#pragma unroll
  for (int k = 0; k < 4; ++k)
    tile[ty + 8 * k][tx] = src[(size_t)(t0 + ty + 8 * k) * ND + d0 + tx];
  __syncthreads();
#pragma unroll
  for (int k = 0; k < 4; ++k)
    dst[(size_t)(d0 + ty + 8 * k) * NS + t0 + tx] = f2bf(tile[tx][ty + 8 * k]);
}

// ---------------- split-bf16 GEMM, C = (Ahi+Alo)(Bhi+Blo)^T (3-term) ----------------
// A: [M][K] bf16 hi/lo, B: [N][K] bf16 hi/lo (B^T form, K contiguous).
// 128x128 tile, BK=32, 4 waves 2x2, each wave 4x4 frags of 16x16x32 MFMA.
// EPI=0: write bf16 hi/lo (for q). EPI=1: write f32.
template <int EPI>
__global__ __launch_bounds__(256) void gemm_split_kernel(
    const u16* __restrict__ Ahi, const u16* __restrict__ Alo,
    const u16* __restrict__ Bhi, const u16* __restrict__ Blo,
    u16* __restrict__ outHi, u16* __restrict__ outLo,
    float* __restrict__ outF, const int K, const int nTN, const int ldc,
    const long aStride, const long bStride, const long cStride) {
  __shared__ u16 lds[4 * 4096];  // Ahi,Alo,Bhi,Blo tiles [128][32] bf16 = 8KB each
  const int t = threadIdx.x;
  const int bz = blockIdx.y;
  const int tm = blockIdx.x / nTN, tn = blockIdx.x % nTN;
  const size_t rowA0 = (size_t)tm * 128, rowB0 = (size_t)tn * 128;
  const u16* pSrc[4];
  pSrc[0] = Ahi + (size_t)bz * aStride + rowA0 * K;
  pSrc[1] = Alo + (size_t)bz * aStride + rowA0 * K;
  pSrc[2] = Bhi + (size_t)bz * bStride + rowB0 * K;
  pSrc[3] = Blo + (size_t)bz * bStride + rowB0 * K;

  const int lane = t & 63, w = t >> 6;
  const int wr = w >> 1, wc = w & 1;
  const int fr = lane & 15, fq = lane >> 4;

  f32x4 acc[4][4] = {};

  for (int k0 = 0; k0 < K; k0 += 32) {
    // stage: 4 tiles x 512 chunks(16B); thread t does 8 chunks, j>>1 selects tile
#pragma unroll
    for (int j = 0; j < 8; ++j) {
      const int tile = j >> 1;
      const int cc = ((j & 1) << 8) | t;      // 0..511 within tile
      const int row = cc >> 2, colE = (cc & 3) * 8;
      bf16x8 v = *(const bf16x8*)(pSrc[tile] + (size_t)row * K + k0 + colE);
      *(bf16x8*)&lds[tile * 4096 + cc * 8] = v;
    }
    __syncthreads();
    bf16x8 ah[4], al[4], bh[4], bl[4];
#pragma unroll
    for (int mi = 0; mi < 4; ++mi) {
      const int r = wr * 64 + mi * 16 + fr;
      ah[mi] = *(const bf16x8*)&lds[0 * 4096 + r * 32 + fq * 8];
      al[mi] = *(const bf16x8*)&lds[1 * 4096 + r * 32 + fq * 8];
    }
#pragma unroll
    for (int ni = 0; ni < 4; ++ni) {
      const int r = wc * 64 + ni * 16 + fr;
      bh[ni] = *(const bf16x8*)&lds[2 * 4096 + r * 32 + fq * 8];
      bl[ni] = *(const bf16x8*)&lds[3 * 4096 + r * 32 + fq * 8];
    }
#pragma unroll
    for (int mi = 0; mi < 4; ++mi)
#pragma unroll
      for (int ni = 0; ni < 4; ++ni) {
        acc[mi][ni] = __builtin_amdgcn_mfma_f32_16x16x32_bf16(ah[mi], bh[ni], acc[mi][ni], 0, 0, 0);
        acc[mi][ni] = __builtin_amdgcn_mfma_f32_16x16x32_bf16(ah[mi], bl[ni], acc[mi][ni], 0, 0, 0);
        acc[mi][ni] = __builtin_amdgcn_mfma_f32_16x16x32_bf16(al[mi], bh[ni], acc[mi][ni], 0, 0, 0);
      }
    __syncthreads();
  }

  // C/D layout (verified m89/m91): col = lane&15, row = (lane>>4)*4 + reg
  const size_t growBase = rowA0 + wr * 64 + fq * 4;
  const size_t gcolBase = rowB0 + wc * 64 + fr;
#pragma unroll
  for (int mi = 0; mi < 4; ++mi)
#pragma unroll
    for (int ni = 0; ni < 4; ++ni)
#pragma unroll
      for (int r = 0; r < 4; ++r) {
        const size_t gr = growBase + mi * 16 + r;
        const size_t gc = gcolBase + ni * 16;
        const float v = acc[mi][ni][r];
        if (EPI == 0) {
          const size_t idx = gr * ldc + gc;
          const u16 h = f2bf(v);
          outHi[idx] = h;
          outLo[idx] = f2bf(v - bf2f(h));
        } else {
          outF[(size_t)bz * cStride + gr * ldc + gc] = v;
        }
      }
}

// ---------------- PV GEMM: C = A(f32, converted) @ Bt^T + bias ----------------
// A: attn [M][K] f32; Bt: text1T [N][K] bf16 (B^T form).
__global__ __launch_bounds__(256) void gemm_pv_kernel(
    const float* __restrict__ A, const u16* __restrict__ Bt,
    const float* __restrict__ bias, float* __restrict__ C,
    const int K, const int nTN, const int ldc,
    const long aStride, const long bStride, const long cStride) {
  __shared__ u16 ldsA[4096];
  __shared__ u16 ldsB[4096];
  const int t = threadIdx.x;
  const int bz = blockIdx.y;
  const int tm = blockIdx.x / nTN, tn = blockIdx.x % nTN;
  const size_t rowA0 = (size_t)tm * 128, rowB0 = (size_t)tn * 128;
  const float* pA = A + (size_t)bz * aStride + rowA0 * K;
  const u16* pB = Bt + (size_t)bz * bStride + rowB0 * K;

  const int lane = t & 63, w = t >> 6;
  const int wr = w >> 1, wc = w & 1;
  const int fr = lane & 15, fq = lane >> 4;

  f32x4 acc[4][4] = {};

  const int ar = t >> 1, ac0 = (t & 1) * 16;
  for (int k0 = 0; k0 < K; k0 += 32) {
    {  // stage A with f32->bf16 convert: thread t covers row t/2, 16 k's
      const float* s = pA + (size_t)ar * K + k0 + ac0;
      f32x4 v0 = *(const f32x4*)(s);
      f32x4 v1 = *(const f32x4*)(s + 4);
      f32x4 v2 = *(const f32x4*)(s + 8);
      f32x4 v3 = *(const f32x4*)(s + 12);
      u16x8 u0, u1;
#pragma unroll
      for (int j = 0; j < 4; ++j) {
        u0[j] = f2bf(v0[j]); u0[j + 4] = f2bf(v1[j]);
        u1[j] = f2bf(v2[j]); u1[j + 4] = f2bf(v3[j]);
      }
      *(u16x8*)&ldsA[ar * 32 + ac0] = u0;
      *(u16x8*)&ldsA[ar * 32 + ac0 + 8] = u1;
    }
#pragma unroll
    for (int j = 0; j < 2; ++j) {  // stage B (bf16 copy)
      const int cc = (j << 8) | t;
      const int row = cc >> 2, colE = (cc & 3) * 8;
      *(bf16x8*)&ldsB[cc * 8] = *(const bf16x8*)(pB + (size_t)row * K + k0 + colE);
    }
    __syncthreads();
    bf16x8 a[4], bb[4];
#pragma unroll
    for (int mi = 0; mi < 4; ++mi)
      a[mi] = *(const bf16x8*)&ldsA[(wr * 64 + mi * 16 + fr) * 32 + fq * 8];
#pragma unroll
    for (int ni = 0; ni < 4; ++ni)
      bb[ni] = *(const bf16x8*)&ldsB[(wc * 64 + ni * 16 + fr) * 32 + fq * 8];
#pragma unroll
    for (int mi = 0; mi < 4; ++mi)
#pragma unroll
      for (int ni = 0; ni < 4; ++ni)
        acc[mi][ni] = __builtin_amdgcn_mfma_f32_16x16x32_bf16(a[mi], bb[ni], acc[mi][ni], 0, 0, 0);
    __syncthreads();
  }

  const size_t growBase = rowA0 + wr * 64 + fq * 4;
  const size_t gcolBase = rowB0 + wc * 64 + fr;
#pragma unroll
  for (int mi = 0; mi < 4; ++mi)
#pragma unroll
    for (int ni = 0; ni < 4; ++ni) {
      const size_t gc = gcolBase + ni * 16;
      const float bv = bias[gc];
#pragma unroll
      for (int r = 0; r < 4; ++r) {
        const size_t gr = growBase + mi * 16 + r;
        C[(size_t)bz * cStride + gr * ldc + gc] = acc[mi][ni][r] + bv;
      }
    }
}

// ---------------- masked row softmax, in place; folds query mask in ----------------
__global__ __launch_bounds__(256) void softmax_kernel(
    float* __restrict__ attn, const float* __restrict__ mask) {
  const int row = blockIdx.x;  // b*2048 + s
  const int b = row >> 11;
  const int s = row & 2047;
  float* p = attn + (size_t)row * NS;
  const float* km = mask + b * NS;
  const float qm = km[s];
  const int t = threadIdx.x;
  f32x4 x0 = ((const f32x4*)p)[2 * t], x1 = ((const f32x4*)p)[2 * t + 1];
  f32x4 m0 = ((const f32x4*)km)[2 * t], m1 = ((const f32x4*)km)[2 * t + 1];
  float mx = -3.0e38f;
#pragma unroll
  for (int j = 0; j < 4; ++j) {
    if (m0[j] != 0.f) mx = fmaxf(mx, x0[j]);
    if (m1[j] != 0.f) mx = fmaxf(mx, x1[j]);
  }
#pragma unroll
  for (int o = 32; o > 0; o >>= 1) mx = fmaxf(mx, __shfl_xor(mx, o));
  __shared__ float red[4];
  if ((t & 63) == 0) red[t >> 6] = mx;
  __syncthreads();
  mx = fmaxf(fmaxf(red[0], red[1]), fmaxf(red[2], red[3]));
  f32x4 e0, e1;
  float sum = 0.f;
#pragma unroll
  for (int j = 0; j < 4; ++j) {
    e0[j] = (m0[j] != 0.f) ? __expf(x0[j] - mx) : 0.f;
    e1[j] = (m1[j] != 0.f) ? __expf(x1[j] - mx) : 0.f;
    sum += e0[j] + e1[j];
  }
#pragma unroll
  for (int o = 32; o > 0; o >>= 1) sum += __shfl_xor(sum, o);
  __syncthreads();
  if ((t & 63) == 0) red[t >> 6] = sum;
  __syncthreads();
  sum = red[0] + red[1] + red[2] + red[3];
  const float sc = (sum > 0.f) ? (qm / sum) : 0.f;
  ((f32x4*)p)[2 * t] = e0 * sc;
  ((f32x4*)p)[2 * t + 1] = e1 * sc;
}

extern "C" void kernel_launch(void* const* d_in, const int* in_sizes, int n_in,
                              void* d_out, int out_size, void* d_ws, size_t ws_size,
                              hipStream_t stream) {
  const float* text = (const float*)d_in[0];
  const float* text1 = (const float*)d_in[1];
  const float* mask = (const float*)d_in[2];
  const float* W = (const float*)d_in[3];
  const float* bias = (const float*)d_in[4];

  float* out0 = (float*)d_out;                       // [8,2048,1024] f32
  float* attn = out0 + (size_t)NB * NS * ND;         // [8,2048,2048] f32

  // scratch choreography:
  //  - text hi/lo live in attn region (dead before K2 writes logits there)
  //  - q hi/lo live in out0 region (dead before K4 writes out0)
  //  - text1 hi/lo, W hi/lo, text1T in ws (~105 MB)
  u16* text_hi = (u16*)attn;
  u16* text_lo = text_hi + (size_t)NB * NS * ND;
  u16* q_hi = (u16*)out0;
  u16* q_lo = q_hi + (size_t)NB * NS * ND;

  u16* wsp = (u16*)d_ws;
  u16* t1_hi = wsp;
  u16* t1_lo = t1_hi + (size_t)NB * NS * ND;
  u16* W_hi = t1_lo + (size_t)NB * NS * ND;
  u16* W_lo = W_hi + (size_t)ND * ND;
  u16* t1T = W_lo + (size_t)ND * ND;

  const int nTok = NB * NS;  // 16384

  split_bf16_kernel<<<2048, 256, 0, stream>>>(text, text_hi, text_lo, nTok * ND / 4);
  split_bf16_kernel<<<2048, 256, 0, stream>>>(text1, t1_hi, t1_lo, nTok * ND / 4);
  split_bf16_kernel<<<512, 256, 0, stream>>>(W, W_hi, W_lo, ND * ND / 4);
  transpose_bf16_kernel<<<dim3(NS / 32, ND / 32, NB), dim3(32, 8), 0, stream>>>(text1, t1T);

  // K1: q = text @ W^T  (M=16384, N=1024, K=1024), q -> hi/lo bf16 in out0 region
  gemm_split_kernel<0><<<dim3((nTok / 128) * (ND / 128), 1), 256, 0, stream>>>(
      text_hi, text_lo, W_hi, W_lo, q_hi, q_lo, nullptr, ND, ND / 128, ND, 0, 0, 0);

  // K2: logits[b] = q[b] @ text1[b]^T (M=N=2048, K=1024) -> attn region f32
  gemm_split_kernel<1><<<dim3((NS / 128) * (NS / 128), NB), 256, 0, stream>>>(
      q_hi, q_lo, t1_hi, t1_lo, nullptr, nullptr, attn, ND, NS / 128, NS,
      (long)NS * ND, (long)NS * ND, (long)NS * NS);

  // K3: masked softmax rows, in place, folds query mask
  softmax_kernel<<<nTok, 256, 0, stream>>>(attn, mask);

  // K4: out0[b] = attn[b] @ text1T[b]^T + bias (M=2048, N=1024, K=2048)
  gemm_pv_kernel<<<dim3((NS / 128) * (ND / 128), NB), 256, 0, stream>>>(
      attn, t1T, bias, out0, NS, ND / 128, ND,
      (long)NS * NS, (long)ND * NS, (long)NS * ND);
}

// Round 2
// 547.406 us; speedup vs baseline: 1.1568x; 1.1568x over previous
//
#include <hip/hip_runtime.h>

typedef unsigned short u16;
typedef unsigned int u32;
typedef __attribute__((ext_vector_type(4))) float f32x4;
typedef __attribute__((ext_vector_type(8))) short bf16x8;   // 8 bf16 (4 VGPRs) MFMA frag
typedef __attribute__((ext_vector_type(4))) u16 u16x4;
typedef __attribute__((ext_vector_type(8))) u16 u16x8;

// B=8, S=2048, D=1024
#define NB 8
#define NS 2048
#define ND 1024

__device__ __forceinline__ u16 f2bf(float x) {  // f32 -> bf16 round-nearest-even
  u32 u = __builtin_bit_cast(u32, x);
  u32 r = 0x7fffu + ((u >> 16) & 1u);
  return (u16)((u + r) >> 16);
}
__device__ __forceinline__ float bf2f(u16 h) {
  return __builtin_bit_cast(float, (u32)h << 16);
}

__device__ __forceinline__ void gload16(const void* g, void* l) {
  __builtin_amdgcn_global_load_lds(
      (const __attribute__((address_space(1))) void*)g,
      (__attribute__((address_space(3))) void*)l, 16, 0, 0);
}

// ---------------- elementwise split: x -> (hi, lo) bf16 ----------------
__global__ __launch_bounds__(256) void split_bf16_kernel(
    const float* __restrict__ x, u16* __restrict__ hi, u16* __restrict__ lo, int n4) {
  int i = blockIdx.x * 256 + threadIdx.x;
  const int stride = gridDim.x * 256;
  for (; i < n4; i += stride) {
    f32x4 v = ((const f32x4*)x)[i];
    u16x4 h, l;
#pragma unroll
    for (int j = 0; j < 4; ++j) {
      float f = v[j];
      u16 hh = f2bf(f);
      h[j] = hh;
      l[j] = f2bf(f - bf2f(hh));
    }
    ((u16x4*)hi)[i] = h;
    ((u16x4*)lo)[i] = l;
  }
}

// ---------------- text1 [b][t][d] f32 -> text1T [b][d][t] bf16 ----------------
__global__ __launch_bounds__(256) void transpose_bf16_kernel(
    const float* __restrict__ t1, u16* __restrict__ t1T) {
  __shared__ float tile[32][33];
  const int b = blockIdx.z;
  const float* src = t1 + (size_t)b * (NS * ND);
  u16* dst = t1T + (size_t)b * (ND * NS);
  const int t0 = blockIdx.x * 32, d0 = blockIdx.y * 32;
  const int tx = threadIdx.x, ty = threadIdx.y;  // (32,8)
#pragma unroll
  for (int k = 0; k < 4; ++k)
    tile[ty + 8 * k][tx] = src[(size_t)(t0 + ty + 8 * k) * ND + d0 + tx];
  __syncthreads();
#pragma unroll
  for (int k = 0; k < 4; ++k)
    dst[(size_t)(d0 + ty + 8 * k) * NS + t0 + tx] = f2bf(tile[tx][ty + 8 * k]);
}

// ============ split-bf16 GEMM v2: 256x256 tile, 8 waves, dbuf + global_load_lds ============
// C = (Ahi+Alo)(Bhi+Blo)^T (3 MFMA terms: hh, hl, lh).
// A: [M][K] bf16 hi/lo, B: [N][K] bf16 hi/lo (B^T form, K contiguous). K=1024, BK=32.
// LDS per operand pair: [256 rows][64] bf16 (row = hi chunks 0-3 | lo chunks 4-7), 128B rows.
// Chunk c of row r is stored at byte r*128 + 16*(c ^ (r&7))  (XOR swizzle, bank-conflict-free).
// global_load_lds writes linearly; the per-lane GLOBAL source is pre-swizzled to compensate.
__device__ __forceinline__ void stage_pair(u16* nA, u16* nB,
                                           const u16* srcA, const u16* srcB,
                                           int k0, int K, int w) {
#pragma unroll
  for (int j = 0; j < 4; ++j)
    gload16(srcA + (size_t)(j * 8) * K + k0, (char*)nA + w * 4096 + j * 1024);
#pragma unroll
  for (int j = 0; j < 4; ++j)
    gload16(srcB + (size_t)(j * 8) * K + k0, (char*)nB + w * 4096 + j * 1024);
}

template <int EPI>  // EPI=0: write bf16 hi/lo (q). EPI=1: write f32 (logits).
__global__ __launch_bounds__(512, 2) void gemm_split2_kernel(
    const u16* __restrict__ Ahi, const u16* __restrict__ Alo,
    const u16* __restrict__ Bhi, const u16* __restrict__ Blo,
    u16* __restrict__ outHi, u16* __restrict__ outLo,
    float* __restrict__ outF, const int K, const int nTN, const int ldc,
    const long aStride, const long bStride, const long cStride) {
  __shared__ __align__(16) u16 lds[2][2][16384];  // [dbuf][A/B][256*64] = 128 KiB
  const int t = threadIdx.x;
  const int bz = blockIdx.y;
  // XCD-aware bijective swizzle (gridDim.x is a multiple of 8)
  const int q8 = gridDim.x >> 3;
  const int xs = ((int)blockIdx.x & 7) * q8 + ((int)blockIdx.x >> 3);
  const int tm = xs / nTN, tn = xs % nTN;
  const size_t rowA0 = (size_t)tm * 256, rowB0 = (size_t)tn * 256;

  const int lane = t & 63, w = t >> 6;   // 8 waves: 2M x 4N
  const int wr = w >> 2, wc = w & 3;
  const int fr = lane & 15, fq = lane >> 4;

  // staging: wave w covers rows w*32 + j*8 + (lane>>3); lane loads chunk (lane&7)^(row&7)
  const int lr = lane >> 3;
  const int lc = (lane & 7) ^ lr;  // 0-3 -> hi array, 4-7 -> lo array
  const u16* srcA = (lc < 4 ? Ahi : Alo) + (size_t)bz * aStride +
                    (rowA0 + (size_t)(w * 32 + lr)) * K + (lc & 3) * 8;
  const u16* srcB = (lc < 4 ? Bhi : Blo) + (size_t)bz * bStride +
                    (rowB0 + (size_t)(w * 32 + lr)) * K + (lc & 3) * 8;

  // fragment-read byte offsets (swizzled); lo variant = hi addr ^ 64
  const int swz = (fr & 7) << 4;
  const int aOff = ((wr * 128 + fr) << 7) + ((fq << 4) ^ swz);
  const int bOff = ((wc * 64 + fr) << 7) + ((fq << 4) ^ swz);

  f32x4 acc[8][4] = {};

  stage_pair((u16*)&lds[0][0][0], (u16*)&lds[0][1][0], srcA, srcB, 0, K, w);
  __syncthreads();

  const int nsteps = K >> 5;
#pragma unroll 2
  for (int s = 0; s < nsteps; ++s) {
    const int cur = s & 1;
    if (s + 1 < nsteps)
      stage_pair((u16*)&lds[cur ^ 1][0][0], (u16*)&lds[cur ^ 1][1][0],
                 srcA, srcB, (s + 1) << 5, K, w);
    const char* bA = (const char*)&lds[cur][0][0];
    const char* bB = (const char*)&lds[cur][1][0];
    bf16x8 bh[4], bl[4];
#pragma unroll
    for (int ni = 0; ni < 4; ++ni) {
      const int ba = bOff + (ni << 11);
      bh[ni] = *(const bf16x8*)(bB + ba);
      bl[ni] = *(const bf16x8*)(bB + (ba ^ 64));
    }
#pragma unroll
    for (int mi = 0; mi < 8; ++mi) {
      const int aa = aOff + (mi << 11);
      bf16x8 ah = *(const bf16x8*)(bA + aa);
      bf16x8 al = *(const bf16x8*)(bA + (aa ^ 64));
#pragma unroll
      for (int ni = 0; ni < 4; ++ni) {
        acc[mi][ni] = __builtin_amdgcn_mfma_f32_16x16x32_bf16(ah, bh[ni], acc[mi][ni], 0, 0, 0);
        acc[mi][ni] = __builtin_amdgcn_mfma_f32_16x16x32_bf16(ah, bl[ni], acc[mi][ni], 0, 0, 0);
        acc[mi][ni] = __builtin_amdgcn_mfma_f32_16x16x32_bf16(al, bh[ni], acc[mi][ni], 0, 0, 0);
      }
    }
    __syncthreads();
  }

  // C/D layout (verified m89/m91): col = lane&15, row = (lane>>4)*4 + reg
  const size_t growBase = rowA0 + wr * 128 + fq * 4;
  const size_t gcolBase = rowB0 + wc * 64 + fr;
#pragma unroll
  for (int mi = 0; mi < 8; ++mi)
#pragma unroll
    for (int ni = 0; ni < 4; ++ni)
#pragma unroll
      for (int r = 0; r < 4; ++r) {
        const size_t gr = growBase + mi * 16 + r;
        const size_t gc = gcolBase + ni * 16;
        const float v = acc[mi][ni][r];
        if (EPI == 0) {
          const size_t idx = gr * ldc + gc;
          const u16 h = f2bf(v);
          outHi[idx] = h;
          outLo[idx] = f2bf(v - bf2f(h));
        } else {
          outF[(size_t)bz * cStride + gr * ldc + gc] = v;
        }
      }
}

// ---------------- PV GEMM: C = A(f32, converted) @ Bt^T + bias ----------------
// A: attn [M][K] f32; Bt: text1T [N][K] bf16 (B^T form). 128x128 tile, 4 waves.
__global__ __launch_bounds__(256) void gemm_pv_kernel(
    const float* __restrict__ A, const u16* __restrict__ Bt,
    const float* __restrict__ bias, float* __restrict__ C,
    const int K, const int nTN, const int ldc,
    const long aStride, const long bStride, const long cStride) {
  __shared__ u16 ldsA[4096];
  __shared__ u16 ldsB[4096];
  const int t = threadIdx.x;
  const int bz = blockIdx.y;
  const int tm = blockIdx.x / nTN, tn = blockIdx.x % nTN;
  const size_t rowA0 = (size_t)tm * 128, rowB0 = (size_t)tn * 128;
  const float* pA = A + (size_t)bz * aStride + rowA0 * K;
  const u16* pB = Bt + (size_t)bz * bStride + rowB0 * K;

  const int lane = t & 63, w = t >> 6;
  const int wr = w >> 1, wc = w & 1;
  const int fr = lane & 15, fq = lane >> 4;

  f32x4 acc[4][4] = {};

  const int ar = t >> 1, ac0 = (t & 1) * 16;
  for (int k0 = 0; k0 < K; k0 += 32) {
    {  // stage A with f32->bf16 convert: thread t covers row t/2, 16 k's
      const float* s = pA + (size_t)ar * K + k0 + ac0;
      f32x4 v0 = *(const f32x4*)(s);
      f32x4 v1 = *(const f32x4*)(s + 4);
      f32x4 v2 = *(const f32x4*)(s + 8);
      f32x4 v3 = *(const f32x4*)(s + 12);
      u16x8 u0, u1;
#pragma unroll
      for (int j = 0; j < 4; ++j) {
        u0[j] = f2bf(v0[j]); u0[j + 4] = f2bf(v1[j]);
        u1[j] = f2bf(v2[j]); u1[j + 4] = f2bf(v3[j]);
      }
      *(u16x8*)&ldsA[ar * 32 + ac0] = u0;
      *(u16x8*)&ldsA[ar * 32 + ac0 + 8] = u1;
    }
#pragma unroll
    for (int j = 0; j < 2; ++j) {  // stage B (bf16 copy)
      const int cc = (j << 8) | t;
      const int row = cc >> 2, colE = (cc & 3) * 8;
      *(bf16x8*)&ldsB[cc * 8] = *(const bf16x8*)(pB + (size_t)row * K + k0 + colE);
    }
    __syncthreads();
    bf16x8 a[4], bb[4];
#pragma unroll
    for (int mi = 0; mi < 4; ++mi)
      a[mi] = *(const bf16x8*)&ldsA[(wr * 64 + mi * 16 + fr) * 32 + fq * 8];
#pragma unroll
    for (int ni = 0; ni < 4; ++ni)
      bb[ni] = *(const bf16x8*)&ldsB[(wc * 64 + ni * 16 + fr) * 32 + fq * 8];
#pragma unroll
    for (int mi = 0; mi < 4; ++mi)
#pragma unroll
      for (int ni = 0; ni < 4; ++ni)
        acc[mi][ni] = __builtin_amdgcn_mfma_f32_16x16x32_bf16(a[mi], bb[ni], acc[mi][ni], 0, 0, 0);
    __syncthreads();
  }

  const size_t growBase = rowA0 + wr * 64 + fq * 4;
  const size_t gcolBase = rowB0 + wc * 64 + fr;
#pragma unroll
  for (int mi = 0; mi < 4; ++mi)
#pragma unroll
    for (int ni = 0; ni < 4; ++ni) {
      const size_t gc = gcolBase + ni * 16;
      const float bv = bias[gc];
#pragma unroll
      for (int r = 0; r < 4; ++r) {
        const size_t gr = growBase + mi * 16 + r;
        C[(size_t)bz * cStride + gr * ldc + gc] = acc[mi][ni][r] + bv;
      }
    }
}

// ---------------- masked row softmax, in place; folds query mask in ----------------
__global__ __launch_bounds__(256) void softmax_kernel(
    float* __restrict__ attn, const float* __restrict__ mask) {
  const int row = blockIdx.x;  // b*2048 + s
  const int b = row >> 11;
  const int s = row & 2047;
  float* p = attn + (size_t)row * NS;
  const float* km = mask + b * NS;
  const float qm = km[s];
  const int t = threadIdx.x;
  f32x4 x0 = ((const f32x4*)p)[2 * t], x1 = ((const f32x4*)p)[2 * t + 1];
  f32x4 m0 = ((const f32x4*)km)[2 * t], m1 = ((const f32x4*)km)[2 * t + 1];
  float mx = -3.0e38f;
#pragma unroll
  for (int j = 0; j < 4; ++j) {
    if (m0[j] != 0.f) mx = fmaxf(mx, x0[j]);
    if (m1[j] != 0.f) mx = fmaxf(mx, x1[j]);
  }
#pragma unroll
  for (int o = 32; o > 0; o >>= 1) mx = fmaxf(mx, __shfl_xor(mx, o));
  __shared__ float red[4];
  if ((t & 63) == 0) red[t >> 6] = mx;
  __syncthreads();
  mx = fmaxf(fmaxf(red[0], red[1]), fmaxf(red[2], red[3]));
  f32x4 e0, e1;
  float sum = 0.f;
#pragma unroll
  for (int j = 0; j < 4; ++j) {
    e0[j] = (m0[j] != 0.f) ? __expf(x0[j] - mx) : 0.f;
    e1[j] = (m1[j] != 0.f) ? __expf(x1[j] - mx) : 0.f;
    sum += e0[j] + e1[j];
  }
#pragma unroll
  for (int o = 32; o > 0; o >>= 1) sum += __shfl_xor(sum, o);
  __syncthreads();
  if ((t & 63) == 0) red[t >> 6] = sum;
  __syncthreads();
  sum = red[0] + red[1] + red[2] + red[3];
  const float sc = (sum > 0.f) ? (qm / sum) : 0.f;
  ((f32x4*)p)[2 * t] = e0 * sc;
  ((f32x4*)p)[2 * t + 1] = e1 * sc;
}

extern "C" void kernel_launch(void* const* d_in, const int* in_sizes, int n_in,
                              void* d_out, int out_size, void* d_ws, size_t ws_size,
                              hipStream_t stream) {
  const float* text = (const float*)d_in[0];
  const float* text1 = (const float*)d_in[1];
  const float* mask = (const float*)d_in[2];
  const float* W = (const float*)d_in[3];
  const float* bias = (const float*)d_in[4];

  float* out0 = (float*)d_out;                       // [8,2048,1024] f32
  float* attn = out0 + (size_t)NB * NS * ND;         // [8,2048,2048] f32

  // scratch choreography:
  //  - text hi/lo live in attn region (dead before K2 writes logits there)
  //  - q hi/lo live in out0 region (dead before K4 writes out0)
  //  - text1 hi/lo, W hi/lo, text1T in ws (~105 MB)
  u16* text_hi = (u16*)attn;
  u16* text_lo = text_hi + (size_t)NB * NS * ND;
  u16* q_hi = (u16*)out0;
  u16* q_lo = q_hi + (size_t)NB * NS * ND;

  u16* wsp = (u16*)d_ws;
  u16* t1_hi = wsp;
  u16* t1_lo = t1_hi + (size_t)NB * NS * ND;
  u16* W_hi = t1_lo + (size_t)NB * NS * ND;
  u16* W_lo = W_hi + (size_t)ND * ND;
  u16* t1T = W_lo + (size_t)ND * ND;

  const int nTok = NB * NS;  // 16384

  split_bf16_kernel<<<2048, 256, 0, stream>>>(text, text_hi, text_lo, nTok * ND / 4);
  split_bf16_kernel<<<2048, 256, 0, stream>>>(text1, t1_hi, t1_lo, nTok * ND / 4);
  split_bf16_kernel<<<512, 256, 0, stream>>>(W, W_hi, W_lo, ND * ND / 4);
  transpose_bf16_kernel<<<dim3(NS / 32, ND / 32, NB), dim3(32, 8), 0, stream>>>(text1, t1T);

  // K1: q = text @ W^T  (M=16384, N=1024, K=1024), q -> hi/lo bf16 in out0 region
  gemm_split2_kernel<0><<<dim3((nTok / 256) * (ND / 256), 1), 512, 0, stream>>>(
      text_hi, text_lo, W_hi, W_lo, q_hi, q_lo, nullptr, ND, ND / 256, ND, 0, 0, 0);

  // K2: logits[b] = q[b] @ text1[b]^T (M=N=2048, K=1024) -> attn region f32
  gemm_split2_kernel<1><<<dim3((NS / 256) * (NS / 256), NB), 512, 0, stream>>>(
      q_hi, q_lo, t1_hi, t1_lo, nullptr, nullptr, attn, ND, NS / 256, NS,
      (long)NS * ND, (long)NS * ND, (long)NS * NS);

  // K3: masked softmax rows, in place, folds query mask
  softmax_kernel<<<nTok, 256, 0, stream>>>(attn, mask);

  // K4: out0[b] = attn[b] @ text1T[b]^T + bias (M=2048, N=1024, K=2048)
  gemm_pv_kernel<<<dim3((NS / 128) * (ND / 128), NB), 256, 0, stream>>>(
      attn, t1T, bias, out0, NS, ND / 128, ND,
      (long)NS * NS, (long)ND * NS, (long)NS * ND);
}

// Round 3
// 444.915 us; speedup vs baseline: 1.4233x; 1.2304x over previous
//
#include <hip/hip_runtime.h>

typedef unsigned short u16;
typedef unsigned int u32;
typedef __attribute__((ext_vector_type(4))) float f32x4;
typedef __attribute__((ext_vector_type(8))) short bf16x8;   // 8 bf16 (4 VGPRs) MFMA frag
typedef __attribute__((ext_vector_type(4))) u16 u16x4;
typedef __attribute__((ext_vector_type(8))) u16 u16x8;

// B=8, S=2048, D=1024
#define NB 8
#define NS 2048
#define ND 1024

__device__ __forceinline__ u16 f2bf(float x) {  // f32 -> bf16 round-nearest-even
  u32 u = __builtin_bit_cast(u32, x);
  u32 r = 0x7fffu + ((u >> 16) & 1u);
  return (u16)((u + r) >> 16);
}
__device__ __forceinline__ float bf2f(u16 h) {
  return __builtin_bit_cast(float, (u32)h << 16);
}

__device__ __forceinline__ void gload16(const void* g, void* l) {
  __builtin_amdgcn_global_load_lds(
      (const __attribute__((address_space(1))) void*)g,
      (__attribute__((address_space(3))) void*)l, 16, 0, 0);
}

// ---------------- elementwise split: x -> (hi, lo) bf16 ----------------
__global__ __launch_bounds__(256) void split_bf16_kernel(
    const float* __restrict__ x, u16* __restrict__ hi, u16* __restrict__ lo, int n4) {
  int i = blockIdx.x * 256 + threadIdx.x;
  const int stride = gridDim.x * 256;
  for (; i < n4; i += stride) {
    f32x4 v = ((const f32x4*)x)[i];
    u16x4 h, l;
#pragma unroll
    for (int j = 0; j < 4; ++j) {
      float f = v[j];
      u16 hh = f2bf(f);
      h[j] = hh;
      l[j] = f2bf(f - bf2f(hh));
    }
    ((u16x4*)hi)[i] = h;
    ((u16x4*)lo)[i] = l;
  }
}

// ---------------- text1 [b][t][d] f32 -> text1T [b][d][t] bf16 ----------------
__global__ __launch_bounds__(256) void transpose_bf16_kernel(
    const float* __restrict__ t1, u16* __restrict__ t1T) {
  __shared__ float tile[32][33];
  const int b = blockIdx.z;
  const float* src = t1 + (size_t)b * (NS * ND);
  u16* dst = t1T + (size_t)b * (ND * NS);
  const int t0 = blockIdx.x * 32, d0 = blockIdx.y * 32;
  const int tx = threadIdx.x, ty = threadIdx.y;  // (32,8)
#pragma unroll
  for (int k = 0; k < 4; ++k)
    tile[ty + 8 * k][tx] = src[(size_t)(t0 + ty + 8 * k) * ND + d0 + tx];
  __syncthreads();
#pragma unroll
  for (int k = 0; k < 4; ++k)
    dst[(size_t)(d0 + ty + 8 * k) * NS + t0 + tx] = f2bf(tile[tx][ty + 8 * k]);
}

// ============ split-bf16 GEMM v2: 256x256 tile, 8 waves, dbuf + global_load_lds ============
// C = (Ahi+Alo)(Bhi+Blo)^T (3 MFMA terms: hh, hl, lh).
// A: [M][K] bf16 hi/lo, B: [N][K] bf16 hi/lo (B^T form, K contiguous). BK=32.
// LDS per operand pair: [256 rows][64] bf16 (row = hi chunks 0-3 | lo chunks 4-7), 128B rows.
// Chunk c of row r is stored at byte r*128 + 16*(c ^ (r&7))  (XOR swizzle, bank-conflict-free).
// global_load_lds writes linearly; the per-lane GLOBAL source is pre-swizzled to compensate.
__device__ __forceinline__ void stage_pair(u16* nA, u16* nB,
                                           const u16* srcA, const u16* srcB,
                                           int k0, int K, int w) {
#pragma unroll
  for (int j = 0; j < 4; ++j)
    gload16(srcA + (size_t)(j * 8) * K + k0, (char*)nA + w * 4096 + j * 1024);
#pragma unroll
  for (int j = 0; j < 4; ++j)
    gload16(srcB + (size_t)(j * 8) * K + k0, (char*)nB + w * 4096 + j * 1024);
}

template <int EPI>  // EPI=0: write bf16 hi/lo (q). EPI=1: write f32 (logits).
__global__ __launch_bounds__(512, 2) void gemm_split2_kernel(
    const u16* __restrict__ Ahi, const u16* __restrict__ Alo,
    const u16* __restrict__ Bhi, const u16* __restrict__ Blo,
    u16* __restrict__ outHi, u16* __restrict__ outLo,
    float* __restrict__ outF, const int K, const int nTN, const int ldc,
    const long aStride, const long bStride, const long cStride) {
  __shared__ __align__(16) u16 lds[2][2][16384];  // [dbuf][A/B][256*64] = 128 KiB
  const int t = threadIdx.x;
  const int bz = blockIdx.y;
  // XCD-aware bijective swizzle (gridDim.x is a multiple of 8)
  const int q8 = gridDim.x >> 3;
  const int xs = ((int)blockIdx.x & 7) * q8 + ((int)blockIdx.x >> 3);
  const int tm = xs / nTN, tn = xs % nTN;
  const size_t rowA0 = (size_t)tm * 256, rowB0 = (size_t)tn * 256;

  const int lane = t & 63, w = t >> 6;   // 8 waves: 2M x 4N
  const int wr = w >> 2, wc = w & 3;
  const int fr = lane & 15, fq = lane >> 4;

  // staging: wave w covers rows w*32 + j*8 + (lane>>3); lane loads chunk (lane&7)^(row&7)
  const int lr = lane >> 3;
  const int lc = (lane & 7) ^ lr;  // 0-3 -> hi array, 4-7 -> lo array
  const u16* srcA = (lc < 4 ? Ahi : Alo) + (size_t)bz * aStride +
                    (rowA0 + (size_t)(w * 32 + lr)) * K + (lc & 3) * 8;
  const u16* srcB = (lc < 4 ? Bhi : Blo) + (size_t)bz * bStride +
                    (rowB0 + (size_t)(w * 32 + lr)) * K + (lc & 3) * 8;

  // fragment-read byte offsets (swizzled); lo variant = hi addr ^ 64
  const int swz = (fr & 7) << 4;
  const int aOff = ((wr * 128 + fr) << 7) + ((fq << 4) ^ swz);
  const int bOff = ((wc * 64 + fr) << 7) + ((fq << 4) ^ swz);

  f32x4 acc[8][4] = {};

  stage_pair((u16*)&lds[0][0][0], (u16*)&lds[0][1][0], srcA, srcB, 0, K, w);
  __syncthreads();

  const int nsteps = K >> 5;
#pragma unroll 2
  for (int s = 0; s < nsteps; ++s) {
    const int cur = s & 1;
    if (s + 1 < nsteps)
      stage_pair((u16*)&lds[cur ^ 1][0][0], (u16*)&lds[cur ^ 1][1][0],
                 srcA, srcB, (s + 1) << 5, K, w);
    const char* bA = (const char*)&lds[cur][0][0];
    const char* bB = (const char*)&lds[cur][1][0];
    bf16x8 bh[4], bl[4];
#pragma unroll
    for (int ni = 0; ni < 4; ++ni) {
      const int ba = bOff + (ni << 11);
      bh[ni] = *(const bf16x8*)(bB + ba);
      bl[ni] = *(const bf16x8*)(bB + (ba ^ 64));
    }
#pragma unroll
    for (int mi = 0; mi < 8; ++mi) {
      const int aa = aOff + (mi << 11);
      bf16x8 ah = *(const bf16x8*)(bA + aa);
      bf16x8 al = *(const bf16x8*)(bA + (aa ^ 64));
#pragma unroll
      for (int ni = 0; ni < 4; ++ni) {
        acc[mi][ni] = __builtin_amdgcn_mfma_f32_16x16x32_bf16(ah, bh[ni], acc[mi][ni], 0, 0, 0);
        acc[mi][ni] = __builtin_amdgcn_mfma_f32_16x16x32_bf16(ah, bl[ni], acc[mi][ni], 0, 0, 0);
        acc[mi][ni] = __builtin_amdgcn_mfma_f32_16x16x32_bf16(al, bh[ni], acc[mi][ni], 0, 0, 0);
      }
    }
    __syncthreads();
  }

  // C/D layout (verified m89/m91): col = lane&15, row = (lane>>4)*4 + reg
  const size_t growBase = rowA0 + wr * 128 + fq * 4;
  const size_t gcolBase = rowB0 + wc * 64 + fr;
#pragma unroll
  for (int mi = 0; mi < 8; ++mi)
#pragma unroll
    for (int ni = 0; ni < 4; ++ni)
#pragma unroll
      for (int r = 0; r < 4; ++r) {
        const size_t gr = growBase + mi * 16 + r;
        const size_t gc = gcolBase + ni * 16;
        const float v = acc[mi][ni][r];
        if (EPI == 0) {
          const size_t idx = gr * ldc + gc;
          const u16 h = f2bf(v);
          outHi[idx] = h;
          outLo[idx] = f2bf(v - bf2f(h));
        } else {
          outF[(size_t)bz * cStride + gr * ldc + gc] = v;
        }
      }
}

// ============ PV GEMM v2: plain bf16, 256x256 tile, 8 waves, dbuf + global_load_lds ============
// C = A @ B^T + bias. A: attn_bf16 [M][K], B: t1T [N][K] bf16. BK=64.
// LDS per operand: [256 rows][128B] (8 chunks = k0..63), XOR swizzle as above.
__device__ __forceinline__ void stage_pv(u16* nA, u16* nB,
                                         const u16* srcA, const u16* srcB,
                                         int k0, int KA, int KB, int w) {
#pragma unroll
  for (int j = 0; j < 4; ++j)
    gload16(srcA + (size_t)(j * 8) * KA + k0, (char*)nA + w * 4096 + j * 1024);
#pragma unroll
  for (int j = 0; j < 4; ++j)
    gload16(srcB + (size_t)(j * 8) * KB + k0, (char*)nB + w * 4096 + j * 1024);
}

__global__ __launch_bounds__(512, 2) void gemm_pv2_kernel(
    const u16* __restrict__ A, const u16* __restrict__ Bt,
    const float* __restrict__ bias, float* __restrict__ C,
    const int K, const int nTN, const int ldc,
    const long aStride, const long bStride, const long cStride) {
  __shared__ __align__(16) u16 lds[2][2][16384];  // [dbuf][A/B][256*64] = 128 KiB
  const int t = threadIdx.x;
  const int bz = blockIdx.y;
  const int q8 = gridDim.x >> 3;
  const int xs = ((int)blockIdx.x & 7) * q8 + ((int)blockIdx.x >> 3);
  const int tm = xs / nTN, tn = xs % nTN;
  const size_t rowA0 = (size_t)tm * 256, rowB0 = (size_t)tn * 256;

  const int lane = t & 63, w = t >> 6;   // 8 waves: 2M x 4N
  const int wr = w >> 2, wc = w & 3;
  const int fr = lane & 15, fq = lane >> 4;

  const int lr = lane >> 3;
  const int lc = (lane & 7) ^ lr;  // chunk 0..7 within 64-elem row
  const u16* srcA = A + (size_t)bz * aStride + (rowA0 + (size_t)(w * 32 + lr)) * K + lc * 8;
  const u16* srcB = Bt + (size_t)bz * bStride + (rowB0 + (size_t)(w * 32 + lr)) * K + lc * 8;

  const int swz = (fr & 7) << 4;
  const int aOff = ((wr * 128 + fr) << 7) + ((fq << 4) ^ swz);
  const int bOff = ((wc * 64 + fr) << 7) + ((fq << 4) ^ swz);

  f32x4 acc[8][4] = {};

  stage_pv((u16*)&lds[0][0][0], (u16*)&lds[0][1][0], srcA, srcB, 0, K, K, w);
  __syncthreads();

  const int nsteps = K >> 6;
#pragma unroll 2
  for (int s = 0; s < nsteps; ++s) {
    const int cur = s & 1;
    if (s + 1 < nsteps)
      stage_pv((u16*)&lds[cur ^ 1][0][0], (u16*)&lds[cur ^ 1][1][0],
               srcA, srcB, (s + 1) << 6, K, K, w);
    const char* bA = (const char*)&lds[cur][0][0];
    const char* bB = (const char*)&lds[cur][1][0];
    bf16x8 b0[4], b1[4];
#pragma unroll
    for (int ni = 0; ni < 4; ++ni) {
      const int ba = bOff + (ni << 11);
      b0[ni] = *(const bf16x8*)(bB + ba);          // k 0..31 (chunk fq)
      b1[ni] = *(const bf16x8*)(bB + (ba ^ 64));   // k 32..63 (chunk fq+4)
    }
#pragma unroll
    for (int mi = 0; mi < 8; ++mi) {
      const int aa = aOff + (mi << 11);
      bf16x8 a0 = *(const bf16x8*)(bA + aa);
      bf16x8 a1 = *(const bf16x8*)(bA + (aa ^ 64));
#pragma unroll
      for (int ni = 0; ni < 4; ++ni) {
        acc[mi][ni] = __builtin_amdgcn_mfma_f32_16x16x32_bf16(a0, b0[ni], acc[mi][ni], 0, 0, 0);
        acc[mi][ni] = __builtin_amdgcn_mfma_f32_16x16x32_bf16(a1, b1[ni], acc[mi][ni], 0, 0, 0);
      }
    }
    __syncthreads();
  }

  const size_t growBase = rowA0 + wr * 128 + fq * 4;
  const size_t gcolBase = rowB0 + wc * 64 + fr;
#pragma unroll
  for (int mi = 0; mi < 8; ++mi)
#pragma unroll
    for (int ni = 0; ni < 4; ++ni) {
      const size_t gc = gcolBase + ni * 16;
      const float bv = bias[gc];
#pragma unroll
      for (int r = 0; r < 4; ++r) {
        const size_t gr = growBase + mi * 16 + r;
        C[(size_t)bz * cStride + gr * ldc + gc] = acc[mi][ni][r] + bv;
      }
    }
}

// ---------------- masked row softmax, in place; folds query mask; emits bf16 copy ----------------
__global__ __launch_bounds__(256) void softmax_kernel(
    float* __restrict__ attn, const float* __restrict__ mask, u16* __restrict__ abf) {
  const int row = blockIdx.x;  // b*2048 + s
  const int b = row >> 11;
  const int s = row & 2047;
  float* p = attn + (size_t)row * NS;
  const float* km = mask + b * NS;
  const float qm = km[s];
  const int t = threadIdx.x;
  f32x4 x0 = ((const f32x4*)p)[2 * t], x1 = ((const f32x4*)p)[2 * t + 1];
  f32x4 m0 = ((const f32x4*)km)[2 * t], m1 = ((const f32x4*)km)[2 * t + 1];
  float mx = -3.0e38f;
#pragma unroll
  for (int j = 0; j < 4; ++j) {
    if (m0[j] != 0.f) mx = fmaxf(mx, x0[j]);
    if (m1[j] != 0.f) mx = fmaxf(mx, x1[j]);
  }
#pragma unroll
  for (int o = 32; o > 0; o >>= 1) mx = fmaxf(mx, __shfl_xor(mx, o));
  __shared__ float red[4];
  if ((t & 63) == 0) red[t >> 6] = mx;
  __syncthreads();
  mx = fmaxf(fmaxf(red[0], red[1]), fmaxf(red[2], red[3]));
  f32x4 e0, e1;
  float sum = 0.f;
#pragma unroll
  for (int j = 0; j < 4; ++j) {
    e0[j] = (m0[j] != 0.f) ? __expf(x0[j] - mx) : 0.f;
    e1[j] = (m1[j] != 0.f) ? __expf(x1[j] - mx) : 0.f;
    sum += e0[j] + e1[j];
  }
#pragma unroll
  for (int o = 32; o > 0; o >>= 1) sum += __shfl_xor(sum, o);
  __syncthreads();
  if ((t & 63) == 0) red[t >> 6] = sum;
  __syncthreads();
  sum = red[0] + red[1] + red[2] + red[3];
  const float sc = (sum > 0.f) ? (qm / sum) : 0.f;
  e0 *= sc;
  e1 *= sc;
  ((f32x4*)p)[2 * t] = e0;
  ((f32x4*)p)[2 * t + 1] = e1;
  u16x8 ub;
#pragma unroll
  for (int j = 0; j < 4; ++j) {
    ub[j] = f2bf(e0[j]);
    ub[j + 4] = f2bf(e1[j]);
  }
  *(u16x8*)(abf + (size_t)row * NS + t * 8) = ub;
}

extern "C" void kernel_launch(void* const* d_in, const int* in_sizes, int n_in,
                              void* d_out, int out_size, void* d_ws, size_t ws_size,
                              hipStream_t stream) {
  const float* text = (const float*)d_in[0];
  const float* text1 = (const float*)d_in[1];
  const float* mask = (const float*)d_in[2];
  const float* W = (const float*)d_in[3];
  const float* bias = (const float*)d_in[4];

  float* out0 = (float*)d_out;                       // [8,2048,1024] f32
  float* attn = out0 + (size_t)NB * NS * ND;         // [8,2048,2048] f32

  // scratch choreography:
  //  - text hi/lo live in attn region (dead before K2 writes logits there)
  //  - q hi/lo live in out0 region (dead before K4 writes out0)
  //  - text1 hi/lo, W hi/lo, text1T in ws (~105 MB)
  //  - attn_bf16 overwrites t1_hi region (dead after K2)
  u16* text_hi = (u16*)attn;
  u16* text_lo = text_hi + (size_t)NB * NS * ND;
  u16* q_hi = (u16*)out0;
  u16* q_lo = q_hi + (size_t)NB * NS * ND;

  u16* wsp = (u16*)d_ws;
  u16* t1_hi = wsp;
  u16* t1_lo = t1_hi + (size_t)NB * NS * ND;
  u16* W_hi = t1_lo + (size_t)NB * NS * ND;
  u16* W_lo = W_hi + (size_t)ND * ND;
  u16* t1T = W_lo + (size_t)ND * ND;
  u16* attn_bf = t1_hi;  // [8,2048,2048] bf16, reuses t1 hi/lo space

  const int nTok = NB * NS;  // 16384

  split_bf16_kernel<<<2048, 256, 0, stream>>>(text, text_hi, text_lo, nTok * ND / 4);
  split_bf16_kernel<<<2048, 256, 0, stream>>>(text1, t1_hi, t1_lo, nTok * ND / 4);
  split_bf16_kernel<<<512, 256, 0, stream>>>(W, W_hi, W_lo, ND * ND / 4);
  transpose_bf16_kernel<<<dim3(NS / 32, ND / 32, NB), dim3(32, 8), 0, stream>>>(text1, t1T);

  // K1: q = text @ W^T  (M=16384, N=1024, K=1024), q -> hi/lo bf16 in out0 region
  gemm_split2_kernel<0><<<dim3((nTok / 256) * (ND / 256), 1), 512, 0, stream>>>(
      text_hi, text_lo, W_hi, W_lo, q_hi, q_lo, nullptr, ND, ND / 256, ND, 0, 0, 0);

  // K2: logits[b] = q[b] @ text1[b]^T (M=N=2048, K=1024) -> attn region f32
  gemm_split2_kernel<1><<<dim3((NS / 256) * (NS / 256), NB), 512, 0, stream>>>(
      q_hi, q_lo, t1_hi, t1_lo, nullptr, nullptr, attn, ND, NS / 256, NS,
      (long)NS * ND, (long)NS * ND, (long)NS * NS);

  // K3: masked softmax rows, in place, folds query mask; emits bf16 copy for PV
  softmax_kernel<<<nTok, 256, 0, stream>>>(attn, mask, attn_bf);

  // K4: out0[b] = attn_bf[b] @ t1T[b]^T + bias (M=2048, N=1024, K=2048)
  gemm_pv2_kernel<<<dim3((NS / 256) * (ND / 256), NB), 512, 0, stream>>>(
      attn_bf, t1T, bias, out0, NS, ND / 256, ND,
      (long)NS * NS, (long)ND * NS, (long)NS * ND);
}